// Round 5
// baseline (9883.283 us; speedup 1.0000x reference)
//
#include <hip/hip_runtime.h>
#include <math.h>

#define BB 4
#define CC 64
#define HH 192
#define WW 192
#define HW (HH*WW)          // 36864
#define HID 128
#define USZ (BB*CC*HW)      // 9437184

__device__ __forceinline__ float gelu_exact(float x) {
    return 0.5f * x * (1.0f + erff(x * 0.70710678118654752f));
}
__device__ __forceinline__ float softplus_f(float x) { return log1pf(expf(x)); }
__device__ __forceinline__ float sigmoid_f(float x) { return 1.0f / (1.0f + expf(-x)); }

__device__ __forceinline__ unsigned short f2bf(float f) {
    unsigned int u = __float_as_uint(f);
    unsigned int r = (u + 0x7fffu + ((u >> 16) & 1u)) >> 16;
    return (unsigned short)r;
}
__device__ __forceinline__ float bf2f(unsigned int bits16) {
    return __uint_as_float(bits16 << 16);
}

__global__ void zero_kernel(float* __restrict__ p, int n) {
    int i = blockIdx.x * 256 + threadIdx.x;
    if (i < n) p[i] = 0.0f;
}

// NCHW [b][c][y][x] -> NHWC [b][y][x][c]
__global__ void convert_kernel(const float* __restrict__ src, float* __restrict__ dst) {
    __shared__ float T[64 * 65];
    const int tid = threadIdx.x;
    const int b = blockIdx.z, y = blockIdx.y, x0 = blockIdx.x * 64;
    // read NCHW: idx -> c = idx>>4, x4 = idx&15 (float4 over x)
    #pragma unroll
    for (int j = 0; j < 4; ++j) {
        int idx = j * 256 + tid;
        int c = idx >> 4, x4 = idx & 15;
        float4 v = *(const float4*)(src + ((size_t)(b * 64 + c)) * HW + y * WW + x0 + 4 * x4);
        T[c * 65 + 4 * x4]     = v.x;
        T[c * 65 + 4 * x4 + 1] = v.y;
        T[c * 65 + 4 * x4 + 2] = v.z;
        T[c * 65 + 4 * x4 + 3] = v.w;
    }
    __syncthreads();
    // write NHWC: g -> pix = g>>4, c4 = g&15 (float4 over c)
    #pragma unroll
    for (int j = 0; j < 4; ++j) {
        int g = j * 256 + tid;
        int pix = g >> 4, c4 = g & 15;
        float4 o;
        o.x = T[(4 * c4) * 65 + pix];
        o.y = T[(4 * c4 + 1) * 65 + pix];
        o.z = T[(4 * c4 + 2) * 65 + pix];
        o.w = T[(4 * c4 + 3) * 65 + pix];
        *(float4*)(dst + ((size_t)b * HW + y * WW + x0 + pix) * 64 + 4 * c4) = o;
    }
}

// prev_probe[b,c,8,8] = 24x24 means of u (NCHW input)
__global__ void probe0_kernel(const float* __restrict__ u, float* __restrict__ prev_probe) {
    int bx = blockIdx.x;                 // b*64+c
    const float* ub = u + (size_t)bx * HW;
    int tid = threadIdx.x, lane = tid & 63, w = tid >> 6;
    for (int j = 0; j < 16; ++j) {
        int cell = w * 16 + j;
        int py = cell >> 3, cx = cell & 7;
        float s = 0.0f;
        #pragma unroll
        for (int k = 0; k < 9; ++k) {
            int q = lane + 64 * k;
            int yy = py * 24 + q / 24;
            int xx = cx * 24 + q % 24;
            s += ub[yy * WW + xx];
        }
        #pragma unroll
        for (int off = 1; off < 64; off <<= 1) s += __shfl_xor(s, off);
        if (lane == 0) prev_probe[bx * 64 + cell] = s * (1.0f / 576.0f);
    }
}

// raw 48x48 sums of u_in -> local_acc[b,c,4,4]  (only for step 0; NCHW input)
__global__ void reduce0_kernel(const float* __restrict__ u, float* __restrict__ local_acc) {
    int bx = blockIdx.x;                 // b*64+c
    const float* ub = u + (size_t)bx * HW;
    int tid = threadIdx.x, lane = tid & 63, w = tid >> 6;
    __shared__ float cs[16];
    for (int j = 0; j < 4; ++j) {
        int cell = w * 4 + j;
        int cy = cell >> 2, cx = cell & 3;
        float s = 0.0f;
        #pragma unroll 4
        for (int k = 0; k < 36; ++k) {
            int q = lane + 64 * k;
            int yy = cy * 48 + q / 48;
            int xx = cx * 48 + q % 48;
            s += ub[yy * WW + xx];
        }
        #pragma unroll
        for (int off = 1; off < 64; off <<= 1) s += __shfl_xor(s, off);
        if (lane == 0) cs[cell] = s;
    }
    __syncthreads();
    if (tid < 16) local_acc[bx * 16 + tid] = cs[tid];
}

// glue: blocks 0-3 = state update for batch b, block 4 = turb stats for PREVIOUS step
__global__ void glue_kernel(const float* __restrict__ gate_w, const float* __restrict__ gate_b,
                            const float* __restrict__ value_w, const float* __restrict__ value_b,
                            const float* __restrict__ local_w, const float* __restrict__ local_b,
                            float* __restrict__ h_state, float* __restrict__ localc,
                            float* __restrict__ local_acc, float* __restrict__ prev_probe,
                            float* __restrict__ probe_acc, float* __restrict__ accs,
                            float* __restrict__ d_scal, int do_state, int do_turb, int step) {
    int blk = blockIdx.x, tid = threadIdx.x;
    __shared__ float lp[1024];
    __shared__ float ps[64];
    __shared__ float sh[8];
    if (blk == 4) {
        if (!do_turb) return;
        float s1 = 0.0f, s2 = 0.0f;
        for (int j = tid; j < 16384; j += 256) {
            float cur = probe_acc[j] * (1.0f / 576.0f);
            float pv = prev_probe[j];
            s1 += fabsf(cur - pv);
            s2 += fabsf(pv);
            prev_probe[j] = cur;
            probe_acc[j] = 0.0f;
        }
        #pragma unroll
        for (int off = 1; off < 64; off <<= 1) {
            s1 += __shfl_xor(s1, off);
            s2 += __shfl_xor(s2, off);
        }
        int w = tid >> 6;
        if ((tid & 63) == 0) { sh[w] = s1; sh[4 + w] = s2; }
        __syncthreads();
        if (tid == 0) {
            s1 = sh[0] + sh[1] + sh[2] + sh[3];
            s2 = sh[4] + sh[5] + sh[6] + sh[7];
            float se = accs[0] * (1.0f / 9437184.0f);
            float le = accs[1] * (1.0f / 9437184.0f);
            float stop = s1 / (s2 + 16384.0f * 1e-8f);
            float dturb = stop + 0.05f * se + 0.01f * le;
            accs[2] += dturb;
            accs[3] += se;
            accs[0] = 0.0f;
            accs[1] = 0.0f;
            if (step == 5) {
                d_scal[0] = accs[2] * (1.0f / 6.0f);
                d_scal[1] = accs[3] * (1.0f / 6.0f);
            }
        }
    } else {
        if (!do_state) return;
        int b = blk;
        #pragma unroll
        for (int j = 0; j < 4; ++j) {
            int idx = tid + 256 * j;
            float s = local_acc[b * 1024 + idx];
            lp[idx] = s * (1.0f / 2304.0f);
            local_acc[b * 1024 + idx] = 0.0f;
        }
        __syncthreads();
        if (tid < 64) {
            float t = 0.0f;
            #pragma unroll
            for (int cell = 0; cell < 16; ++cell) t += lp[tid * 16 + cell];
            ps[tid] = t * (1.0f / 16.0f);
        }
        __syncthreads();
        if (tid < 64) {
            float g = gate_b[tid], v = value_b[tid];
            #pragma unroll 8
            for (int k = 0; k < 64; ++k) {
                float p = ps[k];
                g += p * gate_w[k * 64 + tid];
                v += p * value_w[k * 64 + tid];
            }
            h_state[b * 64 + tid] += sigmoid_f(g) * tanhf(v);
        }
        #pragma unroll
        for (int j = 0; j < 4; ++j) {
            int idx = tid + 256 * j;
            int co = idx >> 4, cell = idx & 15;
            float a = local_b[co];
            #pragma unroll 8
            for (int ci = 0; ci < 64; ++ci) a += local_w[co * 64 + ci] * lp[ci * 16 + cell];
            localc[b * 1024 + idx] = a;
        }
    }
}

// fused step on NHWC src. FINAL=0: NHWC dst; FINAL=1: NCHW dst (last step).
template<int FINAL>
__global__ __launch_bounds__(256, 3) void main_kernel(
    const float* __restrict__ uS, float* __restrict__ uD,
    const float* __restrict__ w1, const float* __restrict__ b1,
    const float* __restrict__ w2, const float* __restrict__ b2,
    const float* __restrict__ h_state, const float* __restrict__ localc,
    const float* __restrict__ norm_w,
    const float* __restrict__ p_ag, const float* __restrict__ p_al,
    const float* __restrict__ p_logdt, const float* __restrict__ diff_w,
    float* __restrict__ probe_acc, float* __restrict__ local_acc,
    float* __restrict__ accs, int do_norm) {
    __shared__ float X[64 * 68];                           // [px][c] pad 68 -> 17408 B
    __shared__ __align__(16) unsigned short hid[64 * 130]; // [px][h] bf16, pad -> 16640 B
    __shared__ float lc[1024];                             // 4096 B
    __shared__ float plds[256];                            // probe partials [c][4 cells]
    __shared__ float plocal[128];                          // local-pool partials [c][2 cells]
    __shared__ float red[256];
    __shared__ float rsum[8];

    const int tid = threadIdx.x;
    const int px = tid & 63;
    const int cg = __builtin_amdgcn_readfirstlane(tid >> 6);
    const int b = blockIdx.z;
    const int y = blockIdx.y;
    const int x0 = blockIdx.x * 64;
    const int x = x0 + px;

    const float* ub = uS + (size_t)b * HW * 64;   // NHWC batch base

    // stage X tile: contiguous 16KB global read, b128 LDS writes
    #pragma unroll
    for (int j = 0; j < 4; ++j) {
        int idx = j * 256 + tid;
        int pix = idx >> 4, c4 = idx & 15;
        float4 v = *(const float4*)(ub + ((size_t)(y * WW + x0 + pix)) * 64 + 4 * c4);
        *(float4*)(X + pix * 68 + 4 * c4) = v;
    }
    #pragma unroll
    for (int i = 0; i < 4; ++i) {
        int idx = tid + 256 * i;
        lc[idx] = localc[b * 1024 + idx];
    }
    plds[tid] = 0.0f;
    if (tid < 128) plocal[tid] = 0.0f;
    __syncthreads();

    float dt = expf(p_logdt[0]);
    dt = fminf(fmaxf(dt, 0.005f), 0.35f);
    const float a_g = softplus_f(p_ag[0]);
    const float a_l = softplus_f(p_al[0]);
    const float dw0 = diff_w[0], dw1 = diff_w[1], dw2 = diff_w[2];

    const int cbase = cg * 16;
    const int hbase = cg * 32;

    // MLP layer 1 (fp32 acc from b128 LDS reads, bf16 store)
    float hacc[32];
    #pragma unroll
    for (int i = 0; i < 32; ++i) hacc[i] = 0.0f;
    #pragma unroll
    for (int t = 0; t < 16; ++t) {
        float4 xv = *(const float4*)(X + px * 68 + 4 * t);
        float xs0 = xv.x, xs1 = xv.y, xs2 = xv.z, xs3 = xv.w;
        int k = 4 * t;
        #pragma unroll
        for (int i = 0; i < 32; ++i) {
            hacc[i] += xs0 * w1[(k    ) * HID + hbase + i];
            hacc[i] += xs1 * w1[(k + 1) * HID + hbase + i];
            hacc[i] += xs2 * w1[(k + 2) * HID + hbase + i];
            hacc[i] += xs3 * w1[(k + 3) * HID + hbase + i];
        }
    }
    {
        unsigned int* hid32 = (unsigned int*)hid;
        #pragma unroll
        for (int t = 0; t < 16; ++t) {
            float h0 = gelu_exact(hacc[2 * t] + b1[hbase + 2 * t]);
            float h1 = gelu_exact(hacc[2 * t + 1] + b1[hbase + 2 * t + 1]);
            unsigned int pk = ((unsigned int)f2bf(h1) << 16) | (unsigned int)f2bf(h0);
            hid32[px * 65 + (hbase >> 1) + t] = pk;
        }
    }
    __syncthreads();

    // Laplacian: 12 neighbors x 4 float4 loads (16 ch each), NHWC
    float acc[16];
    #pragma unroll
    for (int i = 0; i < 16; ++i) acc[i] = 0.0f;
    {
        const float* base = ub + ((size_t)(y * WW + x)) * 64 + cbase;
        auto accum = [&](const float* np, float wt) {
            #pragma unroll
            for (int k = 0; k < 4; ++k) {
                float4 v = *(const float4*)(np + 4 * k);
                acc[4 * k]     += wt * v.x;
                acc[4 * k + 1] += wt * v.y;
                acc[4 * k + 2] += wt * v.z;
                acc[4 * k + 3] += wt * v.w;
            }
        };
        // y-direction (wave-uniform conditions)
        if (y >= 1)       accum(base - 1 * WW * 64, dw0);
        if (y + 1 < HH)   accum(base + 1 * WW * 64, dw0);
        if (y >= 4)       accum(base - 4 * WW * 64, dw1);
        if (y + 4 < HH)   accum(base + 4 * WW * 64, dw1);
        if (y >= 16)      accum(base - 16 * WW * 64, dw2);
        if (y + 16 < HH)  accum(base + 16 * WW * 64, dw2);
        // x-direction (lane-divergent only at edges)
        if (x >= 1)       accum(base - 1 * 64, dw0);
        if (x + 1 < WW)   accum(base + 1 * 64, dw0);
        if (x >= 4)       accum(base - 4 * 64, dw1);
        if (x + 4 < WW)   accum(base + 4 * 64, dw1);
        if (x >= 16)      accum(base - 16 * 64, dw2);
        if (x + 16 < WW)  accum(base + 16 * 64, dw2);
    }
    // center values from LDS
    float cen[16];
    #pragma unroll
    for (int t = 0; t < 4; ++t) {
        float4 v = *(const float4*)(X + px * 68 + cbase + 4 * t);
        cen[4 * t] = v.x; cen[4 * t + 1] = v.y; cen[4 * t + 2] = v.z; cen[4 * t + 3] = v.w;
    }
    const float cterm = -4.0f * (dw0 + dw1 + dw2);
    float dif[16];
    #pragma unroll
    for (int i = 0; i < 16; ++i) dif[i] = 0.25f * (acc[i] + cterm * cen[i]);

    // MLP layer 2 from bf16 hid
    float racc[16];
    #pragma unroll
    for (int i = 0; i < 16; ++i) racc[i] = 0.0f;
    {
        const unsigned int* hid32 = (const unsigned int*)hid;
        #pragma unroll 4
        for (int t = 0; t < 64; ++t) {
            unsigned int pk = hid32[px * 65 + t];
            float hv0 = bf2f(pk & 0xffffu);
            float hv1 = bf2f(pk >> 16);
            int h0 = 2 * t, h1 = 2 * t + 1;
            #pragma unroll
            for (int i = 0; i < 16; ++i) {
                racc[i] += hv0 * w2[h0 * CC + cbase + i];
                racc[i] += hv1 * w2[h1 * CC + cbase + i];
            }
        }
    }

    // bilinear upsample weights (in=4, out=192)
    float srcy = (y + 0.5f) * (1.0f / 48.0f) - 0.5f;
    srcy = fminf(fmaxf(srcy, 0.0f), 3.0f);
    int iy0 = (int)srcy; iy0 = min(iy0, 3);
    float ty = srcy - (float)iy0;
    int iy1 = min(iy0 + 1, 3);
    float srcx = (x + 0.5f) * (1.0f / 48.0f) - 0.5f;
    srcx = fminf(fmaxf(srcx, 0.0f), 3.0f);
    int jx0 = (int)srcx; jx0 = min(jx0, 3);
    float tx = srcx - (float)jx0;
    int jx1 = min(jx0 + 1, 3);
    const float wy0 = 1.0f - ty, wy1 = ty, wx0 = 1.0f - tx, wx1 = tx;
    const int cminp = x0 / 24;
    const int pcell = x / 24 - cminp;   // 0..3
    const int cx0 = x0 / 48;
    const int lcell = x / 48 - cx0;     // 0..1
    const int ycell = y / 48;
    const int pcy = y / 24;

    float sum_du = 0.0f, sum_df = 0.0f, csq = 0.0f;
    float candv[16];
    #pragma unroll
    for (int i = 0; i < 16; ++i) {
        int c = cbase + i;
        float react = racc[i] + b2[c];
        float hs = h_state[b * CC + c];
        const float* L = lc + c * 16;
        float upv = wy0 * (wx0 * L[iy0 * 4 + jx0] + wx1 * L[iy0 * 4 + jx1]) +
                    wy1 * (wx0 * L[iy1 * 4 + jx0] + wx1 * L[iy1 * 4 + jx1]);
        float du = dif[i] + react + a_g * hs + a_l * upv;
        float cand = cen[i] + dt * du;
        candv[i] = cand;
        sum_du += fabsf(du);
        sum_df += fabsf(dif[i]);
        csq += cand * cand;
        // probe partial (on u_cand, PRE-norm): 8-lane segment sums
        float v = cand;
        v += __shfl_xor(v, 1);
        v += __shfl_xor(v, 2);
        v += __shfl_xor(v, 4);
        if ((px & 7) == 0) atomicAdd(&plds[c * 4 + pcell], v);
    }

    float rinv = 1.0f;
    if (do_norm) {
        red[cg * 64 + px] = csq;
        __syncthreads();
        float tot = red[px] + red[64 + px] + red[128 + px] + red[192 + px];
        rinv = 1.0f / sqrtf(tot * (1.0f / 64.0f) + 1e-8f);
    }

    #pragma unroll
    for (int i = 0; i < 16; ++i) {
        int c = cbase + i;
        float o = candv[i];
        if (do_norm) o = o * rinv * norm_w[c];
        candv[i] = o;
        // local-pool partial (on u_next, POST-norm)
        float v = o;
        v += __shfl_xor(v, 1);
        v += __shfl_xor(v, 2);
        v += __shfl_xor(v, 4);
        if ((px & 7) == 0) atomicAdd(&plocal[c * 2 + lcell], v);
    }
    if (FINAL) {
        float* db = uD + (size_t)b * CC * HW;
        #pragma unroll
        for (int i = 0; i < 16; ++i)
            db[(size_t)(cbase + i) * HW + y * WW + x] = candv[i];
    } else {
        float* db = uD + ((size_t)b * HW + y * WW + x) * 64 + cbase;
        #pragma unroll
        for (int t = 0; t < 4; ++t) {
            float4 o4;
            o4.x = candv[4 * t]; o4.y = candv[4 * t + 1];
            o4.z = candv[4 * t + 2]; o4.w = candv[4 * t + 3];
            *(float4*)(db + 4 * t) = o4;
        }
    }

    // block-wide |du|,|diff| sums
    #pragma unroll
    for (int off = 1; off < 64; off <<= 1) {
        sum_du += __shfl_xor(sum_du, off);
        sum_df += __shfl_xor(sum_df, off);
    }
    if ((tid & 63) == 0) { rsum[cg] = sum_du; rsum[4 + cg] = sum_df; }
    __syncthreads();
    if (tid == 0) {
        atomicAdd(&accs[0], rsum[0] + rsum[1] + rsum[2] + rsum[3]);
        atomicAdd(&accs[1], rsum[4] + rsum[5] + rsum[6] + rsum[7]);
    }
    // probe flush
    {
        int c = tid >> 2, ci = tid & 3;
        int cell = cminp + ci;
        int cmaxp = (x0 + 63) / 24;
        if (cell <= cmaxp)
            atomicAdd(&probe_acc[(b * CC + c) * 64 + pcy * 8 + cell], plds[tid]);
    }
    // local-pool flush
    if (tid < 128) {
        int c = tid >> 1, ci = tid & 1;
        atomicAdd(&local_acc[(b * CC + c) * 16 + ycell * 4 + cx0 + ci], plocal[tid]);
    }
}

extern "C" void kernel_launch(void* const* d_in, const int* in_sizes, int n_in,
                              void* d_out, int out_size, void* d_ws, size_t ws_size,
                              hipStream_t stream) {
    const float* u_in    = (const float*)d_in[0];
    const float* w1      = (const float*)d_in[1];
    const float* b1      = (const float*)d_in[2];
    const float* w2      = (const float*)d_in[3];
    const float* b2      = (const float*)d_in[4];
    const float* gate_w  = (const float*)d_in[5];
    const float* gate_b  = (const float*)d_in[6];
    const float* value_w = (const float*)d_in[7];
    const float* value_b = (const float*)d_in[8];
    const float* norm_w  = (const float*)d_in[9];
    const float* local_w = (const float*)d_in[10];
    const float* local_b = (const float*)d_in[11];
    const float* p_ag    = (const float*)d_in[12];
    const float* p_al    = (const float*)d_in[13];
    const float* p_logdt = (const float*)d_in[14];
    const float* diff_w  = (const float*)d_in[15];

    float* ws = (float*)d_ws;
    float* A          = ws;                       // USZ (NHWC scratch)
    float* localc     = ws + USZ;                 // 4096
    float* prev_probe = localc + 4096;            // 16384
    // zero region (contiguous):
    float* local_acc  = prev_probe + 16384;       // 4096
    float* h_state    = local_acc + 4096;         // 256
    float* probe_acc  = h_state + 256;            // 16384
    float* accs       = probe_acc + 16384;        // 4

    float* uout   = (float*)d_out;
    float* B      = uout;                         // d_out region doubles as NHWC scratch
    float* d_scal = uout + USZ;

    zero_kernel<<<81, 256, 0, stream>>>(local_acc, 4096 + 256 + 16384 + 4);
    convert_kernel<<<dim3(3, HH, BB), 256, 0, stream>>>(u_in, B);
    probe0_kernel<<<256, 256, 0, stream>>>(u_in, prev_probe);
    reduce0_kernel<<<256, 256, 0, stream>>>(u_in, local_acc);

    for (int s = 0; s < 6; ++s) {
        glue_kernel<<<5, 256, 0, stream>>>(gate_w, gate_b, value_w, value_b, local_w, local_b,
                                           h_state, localc, local_acc, prev_probe, probe_acc,
                                           accs, d_scal, 1, (s > 0) ? 1 : 0, s - 1);
        const float* src = (s & 1) ? A : B;   // s even: B->A, s odd: A->B (s5: A->uout NCHW)
        if (s < 5) {
            float* dst = (s & 1) ? B : A;
            main_kernel<0><<<dim3(3, HH, BB), 256, 0, stream>>>(
                src, dst, w1, b1, w2, b2, h_state, localc, norm_w,
                p_ag, p_al, p_logdt, diff_w, probe_acc, local_acc, accs, (s & 1));
        } else {
            main_kernel<1><<<dim3(3, HH, BB), 256, 0, stream>>>(
                src, uout, w1, b1, w2, b2, h_state, localc, norm_w,
                p_ag, p_al, p_logdt, diff_w, probe_acc, local_acc, accs, 1);
        }
    }
    glue_kernel<<<5, 256, 0, stream>>>(gate_w, gate_b, value_w, value_b, local_w, local_b,
                                       h_state, localc, local_acc, prev_probe, probe_acc,
                                       accs, d_scal, 0, 1, 5);
}

// Round 6
// 1077.613 us; speedup vs baseline: 9.1715x; 9.1715x over previous
//
#include <hip/hip_runtime.h>
#include <math.h>

#define BB 4
#define CC 64
#define HH 192
#define WW 192
#define HW (HH*WW)          // 36864
#define HID 128
#define USZ (BB*CC*HW)      // 9437184

typedef __attribute__((ext_vector_type(8))) short bf16x8;
typedef __attribute__((ext_vector_type(4))) float f32x4;

__device__ __forceinline__ float gelu_exact(float x) {
    return 0.5f * x * (1.0f + erff(x * 0.70710678118654752f));
}
__device__ __forceinline__ float softplus_f(float x) { return log1pf(expf(x)); }
__device__ __forceinline__ float sigmoid_f(float x) { return 1.0f / (1.0f + expf(-x)); }

__device__ __forceinline__ unsigned short f2bf(float f) {
    unsigned int u = __float_as_uint(f);
    unsigned int r = (u + 0x7fffu + ((u >> 16) & 1u)) >> 16;
    return (unsigned short)r;
}
__device__ __forceinline__ float bf2f(unsigned int bits16) {
    return __uint_as_float(bits16 << 16);
}

__global__ void zero_kernel(float* __restrict__ p, int n) {
    int i = blockIdx.x * 256 + threadIdx.x;
    if (i < n) p[i] = 0.0f;
}

// NCHW [b][c][y][x] -> NHWC [b][y][x][c]
__global__ void convert_kernel(const float* __restrict__ src, float* __restrict__ dst) {
    __shared__ float T[64 * 65];
    const int tid = threadIdx.x;
    const int b = blockIdx.z, y = blockIdx.y, x0 = blockIdx.x * 64;
    #pragma unroll
    for (int j = 0; j < 4; ++j) {
        int idx = j * 256 + tid;
        int c = idx >> 4, x4 = idx & 15;
        float4 v = *(const float4*)(src + ((size_t)(b * 64 + c)) * HW + y * WW + x0 + 4 * x4);
        T[c * 65 + 4 * x4]     = v.x;
        T[c * 65 + 4 * x4 + 1] = v.y;
        T[c * 65 + 4 * x4 + 2] = v.z;
        T[c * 65 + 4 * x4 + 3] = v.w;
    }
    __syncthreads();
    #pragma unroll
    for (int j = 0; j < 4; ++j) {
        int g = j * 256 + tid;
        int pix = g >> 4, c4 = g & 15;
        float4 o;
        o.x = T[(4 * c4) * 65 + pix];
        o.y = T[(4 * c4 + 1) * 65 + pix];
        o.z = T[(4 * c4 + 2) * 65 + pix];
        o.w = T[(4 * c4 + 3) * 65 + pix];
        *(float4*)(dst + ((size_t)b * HW + y * WW + x0 + pix) * 64 + 4 * c4) = o;
    }
}

// prev_probe[b,c,8,8] = 24x24 means of u (NCHW input)
__global__ void probe0_kernel(const float* __restrict__ u, float* __restrict__ prev_probe) {
    int bx = blockIdx.x;
    const float* ub = u + (size_t)bx * HW;
    int tid = threadIdx.x, lane = tid & 63, w = tid >> 6;
    for (int j = 0; j < 16; ++j) {
        int cell = w * 16 + j;
        int py = cell >> 3, cx = cell & 7;
        float s = 0.0f;
        #pragma unroll
        for (int k = 0; k < 9; ++k) {
            int q = lane + 64 * k;
            int yy = py * 24 + q / 24;
            int xx = cx * 24 + q % 24;
            s += ub[yy * WW + xx];
        }
        #pragma unroll
        for (int off = 1; off < 64; off <<= 1) s += __shfl_xor(s, off);
        if (lane == 0) prev_probe[bx * 64 + cell] = s * (1.0f / 576.0f);
    }
}

// raw 48x48 sums of u_in -> local_acc[b,c,4,4] (step 0 only; NCHW input)
__global__ void reduce0_kernel(const float* __restrict__ u, float* __restrict__ local_acc) {
    int bx = blockIdx.x;
    const float* ub = u + (size_t)bx * HW;
    int tid = threadIdx.x, lane = tid & 63, w = tid >> 6;
    __shared__ float cs[16];
    for (int j = 0; j < 4; ++j) {
        int cell = w * 4 + j;
        int cy = cell >> 2, cx = cell & 3;
        float s = 0.0f;
        #pragma unroll 4
        for (int k = 0; k < 36; ++k) {
            int q = lane + 64 * k;
            int yy = cy * 48 + q / 48;
            int xx = cx * 48 + q % 48;
            s += ub[yy * WW + xx];
        }
        #pragma unroll
        for (int off = 1; off < 64; off <<= 1) s += __shfl_xor(s, off);
        if (lane == 0) cs[cell] = s;
    }
    __syncthreads();
    if (tid < 16) local_acc[bx * 16 + tid] = cs[tid];
}

// pack w1/w2 into MFMA B-fragment order (bf16).
// w1f: frag f = w*4 + nt*2 + ks (16 frags): elem (lane l, j) = w1[(ks*32+(l>>4)*8+j)*128 + w*32+nt*16+(l&15)]
// w2f: frag f = w*4 + ks (16 frags):       elem (l, j)      = w2[(ks*32+(l>>4)*8+j)*64  + w*16+(l&15)]
__global__ void fragprep_kernel(const float* __restrict__ w1, const float* __restrict__ w2,
                                unsigned short* __restrict__ w1f, unsigned short* __restrict__ w2f) {
    int e = blockIdx.x * 256 + threadIdx.x;   // 0..16383
    int j = e & 7;
    int l = (e >> 3) & 63;
    int f = e >> 9;                           // 0..31
    int r = l & 15, g = l >> 4;
    if (f < 16) {
        int w_ = f >> 2, nt = (f >> 1) & 1, ks = f & 1;
        int k = ks * 32 + g * 8 + j;
        int h = w_ * 32 + nt * 16 + r;
        w1f[e] = f2bf(w1[k * HID + h]);
    } else {
        int f2 = f - 16;
        int w_ = f2 >> 2, ks = f2 & 3;
        int k = ks * 32 + g * 8 + j;
        int co = w_ * 16 + r;
        w2f[e - 8192] = f2bf(w2[k * CC + co]);
    }
}

// glue: blocks 0-3 = state update for batch b, block 4 = turb stats for PREVIOUS step
__global__ void glue_kernel(const float* __restrict__ gate_w, const float* __restrict__ gate_b,
                            const float* __restrict__ value_w, const float* __restrict__ value_b,
                            const float* __restrict__ local_w, const float* __restrict__ local_b,
                            float* __restrict__ h_state, float* __restrict__ localc,
                            float* __restrict__ local_acc, float* __restrict__ prev_probe,
                            float* __restrict__ probe_acc, float* __restrict__ accs,
                            float* __restrict__ d_scal, int do_state, int do_turb, int step) {
    int blk = blockIdx.x, tid = threadIdx.x;
    __shared__ float lp[1024];
    __shared__ float ps[64];
    __shared__ float sh[8];
    if (blk == 4) {
        if (!do_turb) return;
        float s1 = 0.0f, s2 = 0.0f;
        for (int j = tid; j < 16384; j += 256) {
            float cur = probe_acc[j] * (1.0f / 576.0f);
            float pv = prev_probe[j];
            s1 += fabsf(cur - pv);
            s2 += fabsf(pv);
            prev_probe[j] = cur;
            probe_acc[j] = 0.0f;
        }
        #pragma unroll
        for (int off = 1; off < 64; off <<= 1) {
            s1 += __shfl_xor(s1, off);
            s2 += __shfl_xor(s2, off);
        }
        int w = tid >> 6;
        if ((tid & 63) == 0) { sh[w] = s1; sh[4 + w] = s2; }
        __syncthreads();
        if (tid == 0) {
            s1 = sh[0] + sh[1] + sh[2] + sh[3];
            s2 = sh[4] + sh[5] + sh[6] + sh[7];
            float se = accs[0] * (1.0f / 9437184.0f);
            float le = accs[1] * (1.0f / 9437184.0f);
            float stop = s1 / (s2 + 16384.0f * 1e-8f);
            float dturb = stop + 0.05f * se + 0.01f * le;
            accs[2] += dturb;
            accs[3] += se;
            accs[0] = 0.0f;
            accs[1] = 0.0f;
            if (step == 5) {
                d_scal[0] = accs[2] * (1.0f / 6.0f);
                d_scal[1] = accs[3] * (1.0f / 6.0f);
            }
        }
    } else {
        if (!do_state) return;
        int b = blk;
        #pragma unroll
        for (int j = 0; j < 4; ++j) {
            int idx = tid + 256 * j;
            float s = local_acc[b * 1024 + idx];
            lp[idx] = s * (1.0f / 2304.0f);
            local_acc[b * 1024 + idx] = 0.0f;
        }
        __syncthreads();
        if (tid < 64) {
            float t = 0.0f;
            #pragma unroll
            for (int cell = 0; cell < 16; ++cell) t += lp[tid * 16 + cell];
            ps[tid] = t * (1.0f / 16.0f);
        }
        __syncthreads();
        if (tid < 64) {
            float g = gate_b[tid], v = value_b[tid];
            #pragma unroll 8
            for (int k = 0; k < 64; ++k) {
                float p = ps[k];
                g += p * gate_w[k * 64 + tid];
                v += p * value_w[k * 64 + tid];
            }
            h_state[b * 64 + tid] += sigmoid_f(g) * tanhf(v);
        }
        #pragma unroll
        for (int j = 0; j < 4; ++j) {
            int idx = tid + 256 * j;
            int co = idx >> 4, cell = idx & 15;
            float a = local_b[co];
            #pragma unroll 8
            for (int ci = 0; ci < 64; ++ci) a += local_w[co * 64 + ci] * lp[ci * 16 + cell];
            localc[b * 1024 + idx] = a;
        }
    }
}

__device__ __forceinline__ float4 ld4(const float* p) { return *(const float4*)p; }

// fused step on NHWC src. FINAL=0: NHWC dst; FINAL=1: NCHW dst (last step).
template<int FINAL>
__global__ __launch_bounds__(256, 3) void main_kernel(
    const float* __restrict__ uS, float* __restrict__ uD,
    const unsigned short* __restrict__ w1f, const float* __restrict__ b1,
    const unsigned short* __restrict__ w2f, const float* __restrict__ b2,
    const float* __restrict__ h_state, const float* __restrict__ localc,
    const float* __restrict__ norm_w,
    const float* __restrict__ p_ag, const float* __restrict__ p_al,
    const float* __restrict__ p_logdt, const float* __restrict__ diff_w,
    float* __restrict__ probe_acc, float* __restrict__ local_acc,
    float* __restrict__ accs, int do_norm) {
    __shared__ float X[64 * 68];                 // fp32 [px][c] pad68   17408 B
    __shared__ unsigned short Xb[64 * 68];       // bf16 [px][k] pad68   8704 B (reused as reactb)
    __shared__ unsigned short hidb[64 * 132];    // bf16 [px][h] pad132  16896 B
    __shared__ float lct[16 * 64];               // [cell][c]            4096 B
    __shared__ float hsh[64];
    __shared__ float nwsh[64];
    __shared__ float plds[256];                  // [c][4 pcell]
    __shared__ float plocal[128];                // [c][2 lcell]
    __shared__ float red[64];
    __shared__ float rsum[8];
    unsigned short* reactb = Xb;                 // alias: Xb dead after MLP1

    const int tid = threadIdx.x;
    const int lane = tid & 63;
    const int w = __builtin_amdgcn_readfirstlane(tid >> 6);
    const int b = blockIdx.z, y = blockIdx.y, x0 = blockIdx.x * 64;

    const float* ub = uS + (size_t)b * HW * 64;

    // ---- stage X (fp32 + bf16), lct (transposed), hsh, nwsh ----
    #pragma unroll
    for (int jj = 0; jj < 4; ++jj) {
        int idx = jj * 256 + tid;
        int pix = idx >> 4, cq = idx & 15;
        float4 v = *(const float4*)(ub + ((size_t)(y * WW + x0 + pix)) * 64 + 4 * cq);
        *(float4*)(X + pix * 68 + 4 * cq) = v;
        ushort4 pk;
        pk.x = f2bf(v.x); pk.y = f2bf(v.y); pk.z = f2bf(v.z); pk.w = f2bf(v.w);
        *(ushort4*)(Xb + pix * 68 + 4 * cq) = pk;
    }
    #pragma unroll
    for (int jj = 0; jj < 4; ++jj) {
        int idx = jj * 256 + tid;          // c*16 + cell
        int c = idx >> 4, cell = idx & 15;
        lct[cell * 64 + c] = localc[b * 1024 + idx];
    }
    if (tid < 64) { hsh[tid] = h_state[b * 64 + tid]; nwsh[tid] = norm_w[tid]; }
    plds[tid] = 0.0f;
    if (tid < 128) plocal[tid] = 0.0f;
    __syncthreads();

    const int r = lane & 15, g = lane >> 4;

    // ---- weight fragments (contiguous 16B/lane, L2-hot) ----
    bf16x8 B1f[2][2];
    #pragma unroll
    for (int nt = 0; nt < 2; ++nt)
        #pragma unroll
        for (int ks = 0; ks < 2; ++ks)
            B1f[nt][ks] = *(const bf16x8*)(w1f + (((w * 4 + nt * 2 + ks) * 64 + lane) << 3));
    bf16x8 B2f[4];
    #pragma unroll
    for (int ks = 0; ks < 4; ++ks)
        B2f[ks] = *(const bf16x8*)(w2f + (((w * 4 + ks) * 64 + lane) << 3));

    float b1v0 = b1[w * 32 + r];
    float b1v1 = b1[w * 32 + 16 + r];
    const float b2v = b2[w * 16 + r];

    // ---- MLP1: hid = GELU(X @ W1 + b1), wave w owns h-cols [w*32, w*32+32) ----
    #pragma unroll
    for (int mt = 0; mt < 4; ++mt) {
        bf16x8 A[2];
        #pragma unroll
        for (int ks = 0; ks < 2; ++ks) {
            const unsigned short* p = Xb + (mt * 16 + r) * 68 + ks * 32 + g * 8;
            union { ushort4 q[2]; bf16x8 v; } uu;
            uu.q[0] = *(const ushort4*)p;
            uu.q[1] = *(const ushort4*)(p + 4);
            A[ks] = uu.v;
        }
        #pragma unroll
        for (int nt = 0; nt < 2; ++nt) {
            f32x4 acc = {0.f, 0.f, 0.f, 0.f};
            acc = __builtin_amdgcn_mfma_f32_16x16x32_bf16(A[0], B1f[nt][0], acc, 0, 0, 0);
            acc = __builtin_amdgcn_mfma_f32_16x16x32_bf16(A[1], B1f[nt][1], acc, 0, 0, 0);
            int hcol = w * 32 + nt * 16 + r;
            float bv = nt ? b1v1 : b1v0;
            #pragma unroll
            for (int q = 0; q < 4; ++q) {
                int px = mt * 16 + g * 4 + q;
                hidb[px * 132 + hcol] = f2bf(gelu_exact(acc[q] + bv));
            }
        }
    }
    __syncthreads();

    // ---- MLP2: react = hid @ W2 + b2, wave w owns out-cols [w*16, w*16+16) ----
    #pragma unroll
    for (int mt = 0; mt < 4; ++mt) {
        f32x4 acc = {0.f, 0.f, 0.f, 0.f};
        #pragma unroll
        for (int ks = 0; ks < 4; ++ks) {
            const unsigned short* p = hidb + (mt * 16 + r) * 132 + ks * 32 + g * 8;
            union { ushort4 q[2]; bf16x8 v; } uu;
            uu.q[0] = *(const ushort4*)p;
            uu.q[1] = *(const ushort4*)(p + 4);
            acc = __builtin_amdgcn_mfma_f32_16x16x32_bf16(uu.v, B2f[ks], acc, 0, 0, 0);
        }
        int co = w * 16 + r;
        #pragma unroll
        for (int q = 0; q < 4; ++q) {
            int px = mt * 16 + g * 4 + q;
            reactb[px * 68 + co] = f2bf(acc[q] + b2v);
        }
    }
    __syncthreads();

    // ---- epilogue: thread = (4 px, 4 ch); all global access coalesced ----
    float dt = expf(p_logdt[0]);
    dt = fminf(fmaxf(dt, 0.005f), 0.35f);
    const float a_g = softplus_f(p_ag[0]);
    const float a_l = softplus_f(p_al[0]);
    const float dw0 = diff_w[0], dw1 = diff_w[1], dw2 = diff_w[2];
    const float cterm = -4.0f * (dw0 + dw1 + dw2);

    const int cq = r;                  // channel quad (4*cq..4*cq+3)
    const int pg = g;                  // pixel subgroup 0..3
    const int cminp = x0 / 24;
    const int cx0 = x0 / 48;
    const int ycell = y / 48;
    const int pcy = y / 24;

    float srcy = (y + 0.5f) * (1.0f / 48.0f) - 0.5f;
    srcy = fminf(fmaxf(srcy, 0.0f), 3.0f);
    int iy0 = min((int)srcy, 3);
    float ty = srcy - (float)iy0;
    int iy1 = min(iy0 + 1, 3);
    const float wy0 = 1.0f - ty, wy1 = ty;

    float4 cand[4];
    float sum_du = 0.0f, sum_df = 0.0f;

    #pragma unroll
    for (int p = 0; p < 4; ++p) {
        const int px = p * 16 + w * 4 + pg;
        const int x = x0 + px;
        const float* gb = ub + ((size_t)(y * WW + x)) * 64 + 4 * cq;
        float4 a = {0.f, 0.f, 0.f, 0.f};
        {
            float4 v;
            if (y >= 1)      { v = ld4(gb - 1 * WW * 64);  a.x += dw0*v.x; a.y += dw0*v.y; a.z += dw0*v.z; a.w += dw0*v.w; }
            if (y + 1 < HH)  { v = ld4(gb + 1 * WW * 64);  a.x += dw0*v.x; a.y += dw0*v.y; a.z += dw0*v.z; a.w += dw0*v.w; }
            if (y >= 4)      { v = ld4(gb - 4 * WW * 64);  a.x += dw1*v.x; a.y += dw1*v.y; a.z += dw1*v.z; a.w += dw1*v.w; }
            if (y + 4 < HH)  { v = ld4(gb + 4 * WW * 64);  a.x += dw1*v.x; a.y += dw1*v.y; a.z += dw1*v.z; a.w += dw1*v.w; }
            if (y >= 16)     { v = ld4(gb - 16 * WW * 64); a.x += dw2*v.x; a.y += dw2*v.y; a.z += dw2*v.z; a.w += dw2*v.w; }
            if (y + 16 < HH) { v = ld4(gb + 16 * WW * 64); a.x += dw2*v.x; a.y += dw2*v.y; a.z += dw2*v.z; a.w += dw2*v.w; }
            if (x >= 1)      { v = ld4(gb - 1 * 64);       a.x += dw0*v.x; a.y += dw0*v.y; a.z += dw0*v.z; a.w += dw0*v.w; }
            if (x + 1 < WW)  { v = ld4(gb + 1 * 64);       a.x += dw0*v.x; a.y += dw0*v.y; a.z += dw0*v.z; a.w += dw0*v.w; }
            if (x >= 4)      { v = ld4(gb - 4 * 64);       a.x += dw1*v.x; a.y += dw1*v.y; a.z += dw1*v.z; a.w += dw1*v.w; }
            if (x + 4 < WW)  { v = ld4(gb + 4 * 64);       a.x += dw1*v.x; a.y += dw1*v.y; a.z += dw1*v.z; a.w += dw1*v.w; }
            if (x >= 16)     { v = ld4(gb - 16 * 64);      a.x += dw2*v.x; a.y += dw2*v.y; a.z += dw2*v.z; a.w += dw2*v.w; }
            if (x + 16 < WW) { v = ld4(gb + 16 * 64);      a.x += dw2*v.x; a.y += dw2*v.y; a.z += dw2*v.z; a.w += dw2*v.w; }
        }
        float4 cen = *(const float4*)(X + px * 68 + 4 * cq);
        float4 dif;
        dif.x = 0.25f * (a.x + cterm * cen.x);
        dif.y = 0.25f * (a.y + cterm * cen.y);
        dif.z = 0.25f * (a.z + cterm * cen.z);
        dif.w = 0.25f * (a.w + cterm * cen.w);

        ushort4 rk = *(const ushort4*)(reactb + px * 68 + 4 * cq);

        float srcx = (x + 0.5f) * (1.0f / 48.0f) - 0.5f;
        srcx = fminf(fmaxf(srcx, 0.0f), 3.0f);
        int jx0 = min((int)srcx, 3);
        float tx = srcx - (float)jx0;
        int jx1 = min(jx0 + 1, 3);
        const float wx0 = 1.0f - tx, wx1 = tx;
        float4 t00 = *(const float4*)(lct + (iy0 * 4 + jx0) * 64 + 4 * cq);
        float4 t01 = *(const float4*)(lct + (iy0 * 4 + jx1) * 64 + 4 * cq);
        float4 t10 = *(const float4*)(lct + (iy1 * 4 + jx0) * 64 + 4 * cq);
        float4 t11 = *(const float4*)(lct + (iy1 * 4 + jx1) * 64 + 4 * cq);
        float4 upv;
        upv.x = wy0 * (wx0 * t00.x + wx1 * t01.x) + wy1 * (wx0 * t10.x + wx1 * t11.x);
        upv.y = wy0 * (wx0 * t00.y + wx1 * t01.y) + wy1 * (wx0 * t10.y + wx1 * t11.y);
        upv.z = wy0 * (wx0 * t00.z + wx1 * t01.z) + wy1 * (wx0 * t10.z + wx1 * t11.z);
        upv.w = wy0 * (wx0 * t00.w + wx1 * t01.w) + wy1 * (wx0 * t10.w + wx1 * t11.w);
        float4 hs = *(const float4*)(hsh + 4 * cq);

        float4 du, cd;
        du.x = dif.x + bf2f(rk.x) + a_g * hs.x + a_l * upv.x;  cd.x = cen.x + dt * du.x;
        du.y = dif.y + bf2f(rk.y) + a_g * hs.y + a_l * upv.y;  cd.y = cen.y + dt * du.y;
        du.z = dif.z + bf2f(rk.z) + a_g * hs.z + a_l * upv.z;  cd.z = cen.z + dt * du.z;
        du.w = dif.w + bf2f(rk.w) + a_g * hs.w + a_l * upv.w;  cd.w = cen.w + dt * du.w;
        cand[p] = cd;
        sum_du += fabsf(du.x) + fabsf(du.y) + fabsf(du.z) + fabsf(du.w);
        sum_df += fabsf(dif.x) + fabsf(dif.y) + fabsf(dif.z) + fabsf(dif.w);

        if (do_norm) {
            float csq = cd.x * cd.x + cd.y * cd.y + cd.z * cd.z + cd.w * cd.w;
            csq += __shfl_xor(csq, 1);
            csq += __shfl_xor(csq, 2);
            csq += __shfl_xor(csq, 4);
            csq += __shfl_xor(csq, 8);
            if (cq == 0) red[px] = csq;
        }
        // probe partial (pre-norm): reduce over the 4 pg lanes (same 24-cell)
        float4 pv = cd;
        pv.x += __shfl_xor(pv.x, 16); pv.x += __shfl_xor(pv.x, 32);
        pv.y += __shfl_xor(pv.y, 16); pv.y += __shfl_xor(pv.y, 32);
        pv.z += __shfl_xor(pv.z, 16); pv.z += __shfl_xor(pv.z, 32);
        pv.w += __shfl_xor(pv.w, 16); pv.w += __shfl_xor(pv.w, 32);
        if (pg == 0) {
            int pcell = (x0 + p * 16 + w * 4) / 24 - cminp;
            atomicAdd(&plds[(4 * cq + 0) * 4 + pcell], pv.x);
            atomicAdd(&plds[(4 * cq + 1) * 4 + pcell], pv.y);
            atomicAdd(&plds[(4 * cq + 2) * 4 + pcell], pv.z);
            atomicAdd(&plds[(4 * cq + 3) * 4 + pcell], pv.w);
        }
    }
    __syncthreads();   // red + plds complete

    #pragma unroll
    for (int p = 0; p < 4; ++p) {
        const int px = p * 16 + w * 4 + pg;
        const int x = x0 + px;
        float4 o = cand[p];
        if (do_norm) {
            float rinv = 1.0f / sqrtf(red[px] * (1.0f / 64.0f) + 1e-8f);
            float4 nw = *(const float4*)(nwsh + 4 * cq);
            o.x *= rinv * nw.x; o.y *= rinv * nw.y; o.z *= rinv * nw.z; o.w *= rinv * nw.w;
        }
        if (FINAL) {
            float* db = uD + (size_t)b * CC * HW + y * WW + x;
            db[(4 * cq + 0) * HW] = o.x;
            db[(4 * cq + 1) * HW] = o.y;
            db[(4 * cq + 2) * HW] = o.z;
            db[(4 * cq + 3) * HW] = o.w;
        } else {
            *(float4*)(uD + ((size_t)b * HW + y * WW + x) * 64 + 4 * cq) = o;
        }
        // local-pool partial (post-norm): reduce over 4 pg lanes (same 48-cell)
        float4 pv = o;
        pv.x += __shfl_xor(pv.x, 16); pv.x += __shfl_xor(pv.x, 32);
        pv.y += __shfl_xor(pv.y, 16); pv.y += __shfl_xor(pv.y, 32);
        pv.z += __shfl_xor(pv.z, 16); pv.z += __shfl_xor(pv.z, 32);
        pv.w += __shfl_xor(pv.w, 16); pv.w += __shfl_xor(pv.w, 32);
        if (pg == 0) {
            int lcell = (x0 + p * 16 + w * 4) / 48 - cx0;
            atomicAdd(&plocal[(4 * cq + 0) * 2 + lcell], pv.x);
            atomicAdd(&plocal[(4 * cq + 1) * 2 + lcell], pv.y);
            atomicAdd(&plocal[(4 * cq + 2) * 2 + lcell], pv.z);
            atomicAdd(&plocal[(4 * cq + 3) * 2 + lcell], pv.w);
        }
    }

    // block |du|,|diff| sums
    #pragma unroll
    for (int off = 1; off < 64; off <<= 1) {
        sum_du += __shfl_xor(sum_du, off);
        sum_df += __shfl_xor(sum_df, off);
    }
    if (lane == 0) { rsum[w] = sum_du; rsum[4 + w] = sum_df; }
    __syncthreads();
    if (tid == 0) {
        atomicAdd(&accs[0], rsum[0] + rsum[1] + rsum[2] + rsum[3]);
        atomicAdd(&accs[1], rsum[4] + rsum[5] + rsum[6] + rsum[7]);
    }
    {
        int c = tid >> 2, ci = tid & 3;
        int cell = cminp + ci;
        int cmaxp = (x0 + 63) / 24;
        if (cell <= cmaxp)
            atomicAdd(&probe_acc[(b * CC + c) * 64 + pcy * 8 + cell], plds[tid]);
    }
    if (tid < 128) {
        int c = tid >> 1, ci = tid & 1;
        atomicAdd(&local_acc[(b * CC + c) * 16 + ycell * 4 + cx0 + ci], plocal[tid]);
    }
}

extern "C" void kernel_launch(void* const* d_in, const int* in_sizes, int n_in,
                              void* d_out, int out_size, void* d_ws, size_t ws_size,
                              hipStream_t stream) {
    const float* u_in    = (const float*)d_in[0];
    const float* w1      = (const float*)d_in[1];
    const float* b1      = (const float*)d_in[2];
    const float* w2      = (const float*)d_in[3];
    const float* b2      = (const float*)d_in[4];
    const float* gate_w  = (const float*)d_in[5];
    const float* gate_b  = (const float*)d_in[6];
    const float* value_w = (const float*)d_in[7];
    const float* value_b = (const float*)d_in[8];
    const float* norm_w  = (const float*)d_in[9];
    const float* local_w = (const float*)d_in[10];
    const float* local_b = (const float*)d_in[11];
    const float* p_ag    = (const float*)d_in[12];
    const float* p_al    = (const float*)d_in[13];
    const float* p_logdt = (const float*)d_in[14];
    const float* diff_w  = (const float*)d_in[15];

    float* ws = (float*)d_ws;
    float* A          = ws;                       // USZ (NHWC scratch)
    float* localc     = ws + USZ;                 // 4096
    float* prev_probe = localc + 4096;            // 16384
    // zero region (contiguous):
    float* local_acc  = prev_probe + 16384;       // 4096
    float* h_state    = local_acc + 4096;         // 256
    float* probe_acc  = h_state + 256;            // 16384
    float* accs       = probe_acc + 16384;        // 4
    unsigned short* w1f = (unsigned short*)(accs + 4);   // 8192 ushorts
    unsigned short* w2f = w1f + 8192;                    // 8192 ushorts

    float* uout   = (float*)d_out;
    float* B      = uout;                         // d_out region doubles as NHWC scratch
    float* d_scal = uout + USZ;

    zero_kernel<<<81, 256, 0, stream>>>(local_acc, 4096 + 256 + 16384 + 4);
    fragprep_kernel<<<64, 256, 0, stream>>>(w1, w2, w1f, w2f);
    convert_kernel<<<dim3(3, HH, BB), 256, 0, stream>>>(u_in, B);
    probe0_kernel<<<256, 256, 0, stream>>>(u_in, prev_probe);
    reduce0_kernel<<<256, 256, 0, stream>>>(u_in, local_acc);

    for (int s = 0; s < 6; ++s) {
        glue_kernel<<<5, 256, 0, stream>>>(gate_w, gate_b, value_w, value_b, local_w, local_b,
                                           h_state, localc, local_acc, prev_probe, probe_acc,
                                           accs, d_scal, 1, (s > 0) ? 1 : 0, s - 1);
        const float* src = (s & 1) ? A : B;
        if (s < 5) {
            float* dst = (s & 1) ? B : A;
            main_kernel<0><<<dim3(3, HH, BB), 256, 0, stream>>>(
                src, dst, w1f, b1, w2f, b2, h_state, localc, norm_w,
                p_ag, p_al, p_logdt, diff_w, probe_acc, local_acc, accs, (s & 1));
        } else {
            main_kernel<1><<<dim3(3, HH, BB), 256, 0, stream>>>(
                src, uout, w1f, b1, w2f, b2, h_state, localc, norm_w,
                p_ag, p_al, p_logdt, diff_w, probe_acc, local_acc, accs, 1);
        }
    }
    glue_kernel<<<5, 256, 0, stream>>>(gate_w, gate_b, value_w, value_b, local_w, local_b,
                                       h_state, localc, local_acc, prev_probe, probe_acc,
                                       accs, d_scal, 0, 1, 5);
}